// Round 3
// baseline (389.026 us; speedup 1.0000x reference)
//
#include <hip/hip_runtime.h>

// PatchGram, fused single-dispatch version.
//  - One kernel for both layers: work unit = 36 KB = {1 layer-1 sample} or
//    {2 layer-0 samples side-by-side (threads 0-127 / 128-255)}.
//  - 4704 blocks x 2 units each; BOTH units' 9 float4 loads are issued at
//    block start, so unit 1's 36 KB is in flight during all of unit 0's
//    compute/barrier phases (deep prefetch, no convoy).
//  - Reduction identical to the verified register-direct version:
//    thread owns 4 consecutive channels (9 float4), phase-accumulates
//    locally, butterfly shfl_xor for channel pooling, tiny LDS for the
//    64x9 pooled rows + 16x9 output-pooled rows, dot-product epilogue.

#define N_SAMPLES 6272

constexpr int UNITS0 = N_SAMPLES / 2;       // 3136 dual-sample layer-0 units
constexpr int UNITS  = UNITS0 + N_SAMPLES;  // + 6272 layer-1 units = 9408
constexpr int GRID   = UNITS / 2;           // 4704 blocks, 2 units each

__global__ __launch_bounds__(256) void patchgram_fused(
    const float* __restrict__ f0, const float* __restrict__ f1,
    float* __restrict__ out)
{
    __shared__ float4 fr4[2][64 * 3];   // pooled rows, padded to 12 floats
    __shared__ float4 B4[2][16 * 3];

    const int t = threadIdx.x;

    auto unit_ptr = [&](int u) -> const float4* {
        if (u < UNITS0) {
            const int s = 2 * u + (t >> 7);
            return (const float4*)f0 + (size_t)s * 1152 + (size_t)(t & 127) * 9;
        }
        const int s = u - UNITS0;
        return (const float4*)f1 + (size_t)s * 2304 + (size_t)t * 9;
    };

    auto process = [&](int u, const float4 (&v)[9]) {
        // phase accumulate: phase of (j,comp) = (4j+comp) mod 9
        float acc[9];
#pragma unroll
        for (int p = 0; p < 9; ++p) acc[p] = 0.f;
#pragma unroll
        for (int j = 0; j < 9; ++j) {
            acc[(4 * j + 0) % 9] += v[j].x;
            acc[(4 * j + 1) % 9] += v[j].y;
            acc[(4 * j + 2) % 9] += v[j].z;
            acc[(4 * j + 3) % 9] += v[j].w;
        }
#pragma unroll
        for (int p = 0; p < 9; ++p) acc[p] += __shfl_xor(acc[p], 1);

        if (u < UNITS0) {
            // ---- layer 0: two samples, 128 threads each, K=8 ----
            const int half = t >> 7;
            const int t1   = t & 127;
            const int s    = 2 * u + half;
            if ((t1 & 1) == 0) {
                const int row = t1 >> 1;
                fr4[half][row * 3 + 0] = make_float4(acc[0], acc[1], acc[2], acc[3]);
                fr4[half][row * 3 + 1] = make_float4(acc[4], acc[5], acc[6], acc[7]);
                fr4[half][row * 3 + 2] = make_float4(acc[8], 0.f, 0.f, 0.f);
            }
            __syncthreads();
            {
                const float* fr = (const float*)fr4[half];
                float* Bp = (float*)B4[half];
                int i = t1;
                int dg = i / 9, p = i - dg * 9;
                Bp[dg * 12 + p] = fr[(4*dg+0)*12+p] + fr[(4*dg+1)*12+p]
                                + fr[(4*dg+2)*12+p] + fr[(4*dg+3)*12+p];
                i = t1 + 128;
                if (i < 144) {
                    dg = i / 9; p = i - dg * 9;
                    Bp[dg * 12 + p] = fr[(4*dg+0)*12+p] + fr[(4*dg+1)*12+p]
                                    + fr[(4*dg+2)*12+p] + fr[(4*dg+3)*12+p];
                }
            }
            __syncthreads();
            const int c = t1 >> 1;
            const int dbase = (t1 & 1) * 8;
            const float4 a0 = fr4[half][c * 3 + 0];
            const float4 a1 = fr4[half][c * 3 + 1];
            const float4 a2 = fr4[half][c * 3 + 2];
            float o[8];
#pragma unroll
            for (int jj = 0; jj < 8; ++jj) {
                const int d = dbase + jj;
                const float4 b0 = B4[half][d * 3 + 0];
                const float4 b1 = B4[half][d * 3 + 1];
                const float4 b2 = B4[half][d * 3 + 2];
                o[jj] = (a0.x*b0.x + a0.y*b0.y + a0.z*b0.z + a0.w*b0.w
                       + a1.x*b1.x + a1.y*b1.y + a1.z*b1.z + a1.w*b1.w
                       + a2.x*b2.x) * (1.0f / 2304.0f);   // 1/(36*K^2), K=8
            }
            float* ob = out + (size_t)s * 2048 + c * 16 + dbase;
            ((float4*)ob)[0] = make_float4(o[0], o[1], o[2], o[3]);
            ((float4*)ob)[1] = make_float4(o[4], o[5], o[6], o[7]);
            __syncthreads();   // protect fr4/B4 before next unit reuses them
        } else {
            // ---- layer 1: one sample, 256 threads, K=16 ----
            float acc2[9];
#pragma unroll
            for (int p = 0; p < 9; ++p) acc2[p] = acc[p] + __shfl_xor(acc[p], 2);
            const int s = u - UNITS0;
            if ((t & 3) == 0) {
                const int row = t >> 2;
                fr4[0][row * 3 + 0] = make_float4(acc2[0], acc2[1], acc2[2], acc2[3]);
                fr4[0][row * 3 + 1] = make_float4(acc2[4], acc2[5], acc2[6], acc2[7]);
                fr4[0][row * 3 + 2] = make_float4(acc2[8], 0.f, 0.f, 0.f);
            }
            __syncthreads();
            if (t < 144) {
                const int dg = t / 9, p = t - dg * 9;
                const float* fr = (const float*)fr4[0];
                ((float*)B4[0])[dg*12+p] = fr[(4*dg+0)*12+p] + fr[(4*dg+1)*12+p]
                                         + fr[(4*dg+2)*12+p] + fr[(4*dg+3)*12+p];
            }
            __syncthreads();
            const int c = t >> 2;
            const int dbase = (t & 3) * 4;
            const float4 a0 = fr4[0][c * 3 + 0];
            const float4 a1 = fr4[0][c * 3 + 1];
            const float4 a2 = fr4[0][c * 3 + 2];
            float o[4];
#pragma unroll
            for (int jj = 0; jj < 4; ++jj) {
                const int d = dbase + jj;
                const float4 b0 = B4[0][d * 3 + 0];
                const float4 b1 = B4[0][d * 3 + 1];
                const float4 b2 = B4[0][d * 3 + 2];
                o[jj] = (a0.x*b0.x + a0.y*b0.y + a0.z*b0.z + a0.w*b0.w
                       + a1.x*b1.x + a1.y*b1.y + a1.z*b1.z + a1.w*b1.w
                       + a2.x*b2.x) * (1.0f / 9216.0f);   // 1/(36*K^2), K=16
            }
            float* ob = out + (size_t)s * 2048 + 1024 + c * 16 + dbase;
            *(float4*)ob = make_float4(o[0], o[1], o[2], o[3]);
            __syncthreads();   // protect fr4/B4 before next unit reuses them
        }
    };

    const int u0 = blockIdx.x;          // in [0, 4704): layer 0 or layer 1
    const int u1 = blockIdx.x + GRID;   // in [4704, 9408): always layer 1

    // Issue ALL loads up front: unit 1's 36 KB streams during unit 0's work.
    float4 v0[9], v1[9];
    const float4* g0 = unit_ptr(u0);
#pragma unroll
    for (int j = 0; j < 9; ++j) v0[j] = g0[j];
    const float4* g1 = unit_ptr(u1);
#pragma unroll
    for (int j = 0; j < 9; ++j) v1[j] = g1[j];

    process(u0, v0);
    process(u1, v1);
}

extern "C" void kernel_launch(void* const* d_in, const int* in_sizes, int n_in,
                              void* d_out, int out_size, void* d_ws, size_t ws_size,
                              hipStream_t stream) {
    const float* f0 = (const float*)d_in[0];   // [6272, 512, 3, 3]
    const float* f1 = (const float*)d_in[1];   // [6272, 1024, 3, 3]
    float* out = (float*)d_out;                // [6272, 2, 1024]
    patchgram_fused<<<GRID, 256, 0, stream>>>(f0, f1, out);
}